// Round 9
// baseline (1837.648 us; speedup 1.0000x reference)
//
#include <hip/hip_runtime.h>

#define HW 4096   // 64*64 pixels per (b,c) image

typedef float f4 __attribute__((ext_vector_type(4)));

// ---------------------------------------------------------------------------
// proj v7 (instrumented with reps): q=Wq@x, k=Wk@x, v=Wv@y.
// grid = 768 x 256 (3 blocks/CU). Split = blockIdx>>6: 12 splits of 16
// cout-rows (matrix-aligned: 0-3=q, 4-7=k, 8-11=v); chunk = blockIdx&63
// (256 px). Thread = 8 px (2xf4) x 2 couts. Weights staged once in LDS
// (16 rows x 64 cin, stride 68 to spread banks); main-loop weight reads are
// 2 ds_read_b128 per cb with only 2 distinct addresses per wave (2-way =
// free broadcast). Per cb(4 cin): 8 global f4 input loads + 2 LDS b128 vs
// 64 FMA -> LDS pipe 75%, VALU-bound by design. x re-read 8x = 48MB L2.
// NOTE: no __restrict__ on purpose this round — prevents the compiler from
// hoisting the (rep-invariant) compute out of the reps loop.
// ---------------------------------------------------------------------------
__global__ __launch_bounds__(256, 3) void proj_kernel(
    const float* x, const float* y,
    const float* Wq, const float* Wk, const float* Wv,
    float* qkv, int reps)
{
    __shared__ float wlds[16 * 68];
    const int t     = threadIdx.x;
    const int split = blockIdx.x >> 6;        // 0..11 (uniform)
    const int chunk = blockIdx.x & 63;        // 256-px chunk
    const int m     = split >> 2;             // 0=q 1=k 2=v (uniform)
    const int lr0   = (split & 3) * 16;       // cout base within matrix

    {   // stage weights: 256 f4 = 16 rows x 16 f4
        const float* W = (m == 0) ? Wq : (m == 1) ? Wk : Wv;
        const int row = t >> 4, c4 = t & 15;
        const f4 w = *(const f4*)&W[(lr0 + row) * 64 + c4 * 4];
        *(f4*)&wlds[row * 68 + c4 * 4] = w;
    }
    __syncthreads();

    const int pxg = t & 31;                   // 8-px group
    const int rp  = t >> 5;                   // row-pair 0..7
    const int px0 = chunk * 256 + pxg * 8;
    const int b   = px0 >> 12;
    const int pp  = px0 & 4095;
    const float* src = (m == 2) ? y : x;      // uniform
    const float* sb  = src + (size_t)b * 64 * HW + pp;
    float* dst = qkv + ((size_t)m << 20)
                     + ((size_t)b * 64 + lr0 + rp * 2) * HW + pp;

    for (int rep = 0; rep < reps; ++rep) {
        f4 acc[2][2];
#pragma unroll
        for (int i = 0; i < 2; ++i)
#pragma unroll
            for (int h = 0; h < 2; ++h) acc[i][h] = (f4){0.f, 0.f, 0.f, 0.f};

#pragma unroll
        for (int cb = 0; cb < 16; ++cb) {     // 16 chunks of 4 input channels
            f4 xv[4][2];
#pragma unroll
            for (int c2 = 0; c2 < 4; ++c2) {
                xv[c2][0] = *(const f4*)&sb[(cb * 4 + c2) * HW];
                xv[c2][1] = *(const f4*)&sb[(cb * 4 + c2) * HW + 4];
            }
            const f4 w0 = *(const f4*)&wlds[(rp * 2)     * 68 + cb * 4];
            const f4 w1 = *(const f4*)&wlds[(rp * 2 + 1) * 68 + cb * 4];
#pragma unroll
            for (int c2 = 0; c2 < 4; ++c2)
#pragma unroll
                for (int h = 0; h < 2; ++h) {
                    acc[0][h] += xv[c2][h] * w0[c2];
                    acc[1][h] += xv[c2][h] * w1[c2];
                }
        }

        *(f4*)&dst[0]      = acc[0][0];
        *(f4*)&dst[4]      = acc[0][1];
        *(f4*)&dst[HW]     = acc[1][0];
        *(f4*)&dst[HW + 4] = acc[1][1];
    }
}

// ---------------------------------------------------------------------------
// attn (R8 body, instrumented with reps): per-channel 7x7 window attention,
// LDS k/v tile with zero halo. Inner op: fma + exp2 + add + fma. No clamp
// (|log2e*q*(k+bias)| < ~100 << 128). Staging re-runs each rep (idempotent,
// same values -> cross-rep races benign). No __restrict__ (see proj note).
// ---------------------------------------------------------------------------
__global__ __launch_bounds__(256) void attn_kernel(
    const float* qg, const float* kg, const float* vg,
    const float* rel_h, const float* rel_w,
    float* out, int reps)
{
    __shared__ float kT[22 * 72];
    __shared__ float vT[22 * 72];

    const int blk = blockIdx.x;
    const int bc  = blk >> 2;            // b*64 + c
    const int h0  = (blk & 3) << 4;
    const int c   = bc & 63;
    const int t   = threadIdx.x;

    const float* kimg = kg + (size_t)bc * HW;
    const float* vimg = vg + (size_t)bc * HW;
    const f4 z4 = {0.f, 0.f, 0.f, 0.f};
    const float LOG2E = 1.4426950408889634f;

    const int r  = t >> 4;               // 0..15
    const int w0 = (t & 15) << 2;
    const int h  = h0 + r;

    for (int rep = 0; rep < reps; ++rep) {
        __syncthreads();                 // LDS safety across reps

        if (t < 88) {                    // horizontal halo zero
            const int row = t >> 2, side = (t >> 1) & 1, arr = t & 1;
            float* dstl = arr ? vT : kT;
            *(f4*)&dstl[row * 72 + side * 68] = z4;
        }
#pragma unroll
        for (int j = 0; j < 2; ++j) {    // interior: 22 rows x 16 f4 chunks
            const int idx = j * 256 + t;
            if (idx < 352) {
                const int row = idx >> 4, ch = idx & 15;
                const int hy = h0 - 3 + row;
                const bool rv = ((unsigned)hy < 64u);
                const f4 kv = rv ? *(const f4*)&kimg[hy * 64 + ch * 4] : z4;
                const f4 vv = rv ? *(const f4*)&vimg[hy * 64 + ch * 4] : z4;
                *(f4*)&kT[row * 72 + ch * 4 + 4] = kv;
                *(f4*)&vT[row * 72 + ch * 4 + 4] = vv;
            }
        }
        __syncthreads();

        const f4 qv = *(const f4*)&qg[(size_t)bc * HW + h * 64 + w0];
        float qe[4];
#pragma unroll
        for (int p = 0; p < 4; ++p) qe[p] = qv[p] * LOG2E;

        float qb[7][4];
        if (c < 32) {
#pragma unroll
            for (int a = 0; a < 7; ++a) {
                const float bb = rel_h[c * 7 + a];
#pragma unroll
                for (int p = 0; p < 4; ++p) qb[a][p] = qe[p] * bb;
            }
        } else {
#pragma unroll
            for (int j = 0; j < 7; ++j) {
                const float bb = rel_w[(c - 32) * 7 + j];
#pragma unroll
                for (int p = 0; p < 4; ++p) qb[j][p] = qe[p] * bb;
            }
        }

        float l[4] = {0.f, 0.f, 0.f, 0.f};
        float o[4] = {0.f, 0.f, 0.f, 0.f};

        if (c < 32) {
#pragma unroll
            for (int a = 0; a < 7; ++a) {
                const int ro = (r + a) * 72 + w0;
                const f4 k0 = *(const f4*)&kT[ro];
                const f4 k1 = *(const f4*)&kT[ro + 4];
                const f4 k2 = *(const f4*)&kT[ro + 8];
                const f4 v0 = *(const f4*)&vT[ro];
                const f4 v1 = *(const f4*)&vT[ro + 4];
                const f4 v2 = *(const f4*)&vT[ro + 8];
                const float kw[12] = {k0[0], k0[1], k0[2], k0[3], k1[0], k1[1], k1[2], k1[3],
                                      k2[0], k2[1], k2[2], k2[3]};
                const float vw[12] = {v0[0], v0[1], v0[2], v0[3], v1[0], v1[1], v1[2], v1[3],
                                      v2[0], v2[1], v2[2], v2[3]};
#pragma unroll
                for (int b2 = 0; b2 < 7; ++b2)
#pragma unroll
                    for (int p = 0; p < 4; ++p) {
                        const float s = fmaf(qe[p], kw[p + b2 + 1], qb[a][p]);
                        const float e = __builtin_amdgcn_exp2f(s);
                        l[p] += e;
                        o[p] = fmaf(e, vw[p + b2 + 1], o[p]);
                    }
            }
        } else {
#pragma unroll
            for (int a = 0; a < 7; ++a) {
                const int ro = (r + a) * 72 + w0;
                const f4 k0 = *(const f4*)&kT[ro];
                const f4 k1 = *(const f4*)&kT[ro + 4];
                const f4 k2 = *(const f4*)&kT[ro + 8];
                const f4 v0 = *(const f4*)&vT[ro];
                const f4 v1 = *(const f4*)&vT[ro + 4];
                const f4 v2 = *(const f4*)&vT[ro + 8];
                const float kw[12] = {k0[0], k0[1], k0[2], k0[3], k1[0], k1[1], k1[2], k1[3],
                                      k2[0], k2[1], k2[2], k2[3]};
                const float vw[12] = {v0[0], v0[1], v0[2], v0[3], v1[0], v1[1], v1[2], v1[3],
                                      v2[0], v2[1], v2[2], v2[3]};
#pragma unroll
                for (int b2 = 0; b2 < 7; ++b2)
#pragma unroll
                    for (int p = 0; p < 4; ++p) {
                        const float s = fmaf(qe[p], kw[p + b2 + 1], qb[b2][p]);
                        const float e = __builtin_amdgcn_exp2f(s);
                        l[p] += e;
                        o[p] = fmaf(e, vw[p + b2 + 1], o[p]);
                    }
            }
        }

        f4 res;
#pragma unroll
        for (int p = 0; p < 4; ++p)
            res[p] = o[p] * __builtin_amdgcn_rcpf(l[p]);
        *(f4*)&out[(size_t)bc * HW + h * 64 + w0] = res;
    }
}

// ---------------------------------------------------------------------------
extern "C" void kernel_launch(void* const* d_in, const int* in_sizes, int n_in,
                              void* d_out, int out_size, void* d_ws, size_t ws_size,
                              hipStream_t stream) {
    const float* x   = (const float*)d_in[0];
    const float* y   = (const float*)d_in[1];
    const float* Wq  = (const float*)d_in[2];
    const float* Wk  = (const float*)d_in[3];
    const float* Wv  = (const float*)d_in[4];
    const float* rlh = (const float*)d_in[5];
    const float* rlw = (const float*)d_in[6];
    float* out = (float*)d_out;

    float* qkv = (float*)d_ws;        // q | k | v, 4 MB each, contiguous
    float* q = qkv;
    float* k = qkv + (1 << 20);
    float* v = qkv + (2 << 20);

    // MEASUREMENT ROUND: reps amplify each kernel past the 40us profiler
    // cutoff so both get full per-dispatch counters. reps=16/14 chosen so
    // even optimistic per-rep times stay visible. Next round: reps=1.
    proj_kernel<<<768, 256, 0, stream>>>(x, y, Wq, Wk, Wv, qkv, 16);
    attn_kernel<<<1024, 256, 0, stream>>>(q, k, v, rlh, rlw, out, 14);
}

// Round 10
// 98.907 us; speedup vs baseline: 18.5796x; 18.5796x over previous
//
#include <hip/hip_runtime.h>

#define HW 4096   // 64*64 pixels per (b,c) image

typedef float f4 __attribute__((ext_vector_type(4)));

// ---------------------------------------------------------------------------
// proj v8: compulsory-memory-traffic design (R9 counters: v7 was L2-thrash
// bound — 165MB/rep FETCH from 12 cout-splits re-reading x/y; VALUBusy 2.7%,
// zero bank conflicts). Fix: each block owns a DISJOINT 32-px slice and
// computes ALL cout-rows for it -> x,y fetched from HBM exactly once (8MB),
// stores are full 128B lines (12MB, no RFO). One dispatch, two families:
//   blocks 0..511:  q,k from x. thread = 4 px (f4) x 4 rows; cg=t>>3.
//   blocks 512..1023: v from y. thread = 4 px (f4) x 2 rows.
// No LDS (per-CU LDS pipe can't feed operands at FMA rate; L1 broadcast
// can: weight loads have 8 lanes/address, input loads 1 line/wave-instr).
// Per cb (8 cin): 16 VMEM instr vs 128 v_fma (1:8). ~75 VGPR, no spill.
// ---------------------------------------------------------------------------
__global__ __launch_bounds__(256) void proj_kernel(
    const float* __restrict__ x, const float* __restrict__ y,
    const float* __restrict__ Wq, const float* __restrict__ Wk,
    const float* __restrict__ Wv,
    float* __restrict__ qkv)     // q | k | v, each 1<<20 floats
{
    const int t   = threadIdx.x;
    const int blk = blockIdx.x;
    const int pxq = t & 7;                   // f4-quad within the 32-px tile
    const int cg  = t >> 3;                  // 0..31

    if (blk < 512) {
        // ---------------- family A: q,k from x ----------------
        const int p0 = blk * 32;             // disjoint 32-px slice
        const int b  = p0 >> 12;
        const int pp = (p0 & 4095) + pxq * 4;
        const int r0 = cg * 4;               // rows r0..r0+3 of [q(0-63)|k(64-127)]
        const float* xb = x + (size_t)b * 64 * HW + pp;
        // per-thread weight base (4-aligned rows never straddle the q/k seam)
        const float* Wb = (r0 < 64) ? (Wq + r0 * 64) : (Wk + (r0 - 64) * 64);

        f4 acc[4];
#pragma unroll
        for (int j = 0; j < 4; ++j) acc[j] = (f4){0.f, 0.f, 0.f, 0.f};

#pragma unroll
        for (int cb = 0; cb < 8; ++cb) {     // 8 chunks of 8 input channels
            f4 xv[8];
#pragma unroll
            for (int c2 = 0; c2 < 8; ++c2)
                xv[c2] = *(const f4*)&xb[(cb * 8 + c2) * HW];
#pragma unroll
            for (int j = 0; j < 4; ++j) {
                const float* wr = Wb + j * 64 + cb * 8;
                const f4 w0 = *(const f4*)&wr[0];
                const f4 w1 = *(const f4*)&wr[4];
#pragma unroll
                for (int c2 = 0; c2 < 4; ++c2) {
                    acc[j] += xv[c2] * w0[c2];
                    acc[j] += xv[c2 + 4] * w1[c2];
                }
            }
        }

        const int m = (r0 >= 64);            // 0=q, 1=k
        float* dst = qkv + ((size_t)m << 20)
                         + ((size_t)b * 64 + (r0 & 63)) * HW + pp;
#pragma unroll
        for (int j = 0; j < 4; ++j)
            *(f4*)&dst[(size_t)j * HW] = acc[j];
    } else {
        // ---------------- family B: v from y ----------------
        const int p0 = (blk - 512) * 32;
        const int b  = p0 >> 12;
        const int pp = (p0 & 4095) + pxq * 4;
        const int r0 = cg * 2;               // rows r0..r0+1 of v(0-63)
        const float* yb = y + (size_t)b * 64 * HW + pp;
        const float* Wb = Wv + r0 * 64;

        f4 acc[2];
#pragma unroll
        for (int j = 0; j < 2; ++j) acc[j] = (f4){0.f, 0.f, 0.f, 0.f};

#pragma unroll
        for (int cb = 0; cb < 8; ++cb) {
            f4 yv[8];
#pragma unroll
            for (int c2 = 0; c2 < 8; ++c2)
                yv[c2] = *(const f4*)&yb[(cb * 8 + c2) * HW];
#pragma unroll
            for (int j = 0; j < 2; ++j) {
                const float* wr = Wb + j * 64 + cb * 8;
                const f4 w0 = *(const f4*)&wr[0];
                const f4 w1 = *(const f4*)&wr[4];
#pragma unroll
                for (int c2 = 0; c2 < 4; ++c2) {
                    acc[j] += yv[c2] * w0[c2];
                    acc[j] += yv[c2 + 4] * w1[c2];
                }
            }
        }

        float* dst = qkv + ((size_t)2 << 20)
                         + ((size_t)b * 64 + r0) * HW + pp;
#pragma unroll
        for (int j = 0; j < 2; ++j)
            *(f4*)&dst[(size_t)j * HW] = acc[j];
    }
}

// ---------------------------------------------------------------------------
// attn (R8/R9-proven body, reps removed): per-channel 7x7 window attention,
// LDS k/v tile with zero halo. Inner op: fma + exp2 + add + fma. No clamp
// (|log2e*q*(k+bias)| < ~100 << 128 -> exp2 overflow impossible).
// grid = 1024 (b, c, 16-row band), block 256, thread = 4 px. ~8us measured.
// ---------------------------------------------------------------------------
__global__ __launch_bounds__(256) void attn_kernel(
    const float* __restrict__ qg, const float* __restrict__ kg,
    const float* __restrict__ vg,
    const float* __restrict__ rel_h, const float* __restrict__ rel_w,
    float* __restrict__ out)
{
    __shared__ float kT[22 * 72];
    __shared__ float vT[22 * 72];

    const int blk = blockIdx.x;
    const int bc  = blk >> 2;            // b*64 + c
    const int h0  = (blk & 3) << 4;
    const int c   = bc & 63;
    const int t   = threadIdx.x;

    const float* kimg = kg + (size_t)bc * HW;
    const float* vimg = vg + (size_t)bc * HW;
    const f4 z4 = {0.f, 0.f, 0.f, 0.f};

    if (t < 88) {                        // horizontal halo zero
        const int row = t >> 2, side = (t >> 1) & 1, arr = t & 1;
        float* dst = arr ? vT : kT;
        *(f4*)&dst[row * 72 + side * 68] = z4;
    }
#pragma unroll
    for (int j = 0; j < 2; ++j) {        // interior: 22 rows x 16 f4 chunks
        const int idx = j * 256 + t;
        if (idx < 352) {
            const int row = idx >> 4, ch = idx & 15;
            const int hy = h0 - 3 + row;
            const bool rv = ((unsigned)hy < 64u);
            const f4 kv = rv ? *(const f4*)&kimg[hy * 64 + ch * 4] : z4;
            const f4 vv = rv ? *(const f4*)&vimg[hy * 64 + ch * 4] : z4;
            *(f4*)&kT[row * 72 + ch * 4 + 4] = kv;
            *(f4*)&vT[row * 72 + ch * 4 + 4] = vv;
        }
    }
    __syncthreads();

    const int r  = t >> 4;               // 0..15
    const int w0 = (t & 15) << 2;
    const int h  = h0 + r;

    const float LOG2E = 1.4426950408889634f;
    const f4 qv = *(const f4*)&qg[(size_t)bc * HW + h * 64 + w0];
    float qe[4];
#pragma unroll
    for (int p = 0; p < 4; ++p) qe[p] = qv[p] * LOG2E;

    float qb[7][4];
    if (c < 32) {
#pragma unroll
        for (int a = 0; a < 7; ++a) {
            const float bb = rel_h[c * 7 + a];
#pragma unroll
            for (int p = 0; p < 4; ++p) qb[a][p] = qe[p] * bb;
        }
    } else {
#pragma unroll
        for (int j = 0; j < 7; ++j) {
            const float bb = rel_w[(c - 32) * 7 + j];
#pragma unroll
            for (int p = 0; p < 4; ++p) qb[j][p] = qe[p] * bb;
        }
    }

    float l[4] = {0.f, 0.f, 0.f, 0.f};
    float o[4] = {0.f, 0.f, 0.f, 0.f};

    if (c < 32) {
#pragma unroll
        for (int a = 0; a < 7; ++a) {
            const int ro = (r + a) * 72 + w0;
            const f4 k0 = *(const f4*)&kT[ro];
            const f4 k1 = *(const f4*)&kT[ro + 4];
            const f4 k2 = *(const f4*)&kT[ro + 8];
            const f4 v0 = *(const f4*)&vT[ro];
            const f4 v1 = *(const f4*)&vT[ro + 4];
            const f4 v2 = *(const f4*)&vT[ro + 8];
            const float kw[12] = {k0[0], k0[1], k0[2], k0[3], k1[0], k1[1], k1[2], k1[3],
                                  k2[0], k2[1], k2[2], k2[3]};
            const float vw[12] = {v0[0], v0[1], v0[2], v0[3], v1[0], v1[1], v1[2], v1[3],
                                  v2[0], v2[1], v2[2], v2[3]};
#pragma unroll
            for (int b2 = 0; b2 < 7; ++b2)
#pragma unroll
                for (int p = 0; p < 4; ++p) {
                    const float s = fmaf(qe[p], kw[p + b2 + 1], qb[a][p]);
                    const float e = __builtin_amdgcn_exp2f(s);
                    l[p] += e;
                    o[p] = fmaf(e, vw[p + b2 + 1], o[p]);
                }
        }
    } else {
#pragma unroll
        for (int a = 0; a < 7; ++a) {
            const int ro = (r + a) * 72 + w0;
            const f4 k0 = *(const f4*)&kT[ro];
            const f4 k1 = *(const f4*)&kT[ro + 4];
            const f4 k2 = *(const f4*)&kT[ro + 8];
            const f4 v0 = *(const f4*)&vT[ro];
            const f4 v1 = *(const f4*)&vT[ro + 4];
            const f4 v2 = *(const f4*)&vT[ro + 8];
            const float kw[12] = {k0[0], k0[1], k0[2], k0[3], k1[0], k1[1], k1[2], k1[3],
                                  k2[0], k2[1], k2[2], k2[3]};
            const float vw[12] = {v0[0], v0[1], v0[2], v0[3], v1[0], v1[1], v1[2], v1[3],
                                  v2[0], v2[1], v2[2], v2[3]};
#pragma unroll
            for (int b2 = 0; b2 < 7; ++b2)
#pragma unroll
                for (int p = 0; p < 4; ++p) {
                    const float s = fmaf(qe[p], kw[p + b2 + 1], qb[b2][p]);
                    const float e = __builtin_amdgcn_exp2f(s);
                    l[p] += e;
                    o[p] = fmaf(e, vw[p + b2 + 1], o[p]);
                }
        }
    }

    f4 res;
#pragma unroll
    for (int p = 0; p < 4; ++p)
        res[p] = o[p] * __builtin_amdgcn_rcpf(l[p]);
    *(f4*)&out[(size_t)bc * HW + h * 64 + w0] = res;
}

// ---------------------------------------------------------------------------
extern "C" void kernel_launch(void* const* d_in, const int* in_sizes, int n_in,
                              void* d_out, int out_size, void* d_ws, size_t ws_size,
                              hipStream_t stream) {
    const float* x   = (const float*)d_in[0];
    const float* y   = (const float*)d_in[1];
    const float* Wq  = (const float*)d_in[2];
    const float* Wk  = (const float*)d_in[3];
    const float* Wv  = (const float*)d_in[4];
    const float* rlh = (const float*)d_in[5];
    const float* rlw = (const float*)d_in[6];
    float* out = (float*)d_out;

    float* qkv = (float*)d_ws;        // q | k | v, 4 MB each, contiguous
    float* q = qkv;
    float* k = qkv + (1 << 20);
    float* v = qkv + (2 << 20);

    proj_kernel<<<1024, 256, 0, stream>>>(x, y, Wq, Wk, Wv, qkv);
    attn_kernel<<<1024, 256, 0, stream>>>(q, k, v, rlh, rlw, out);
}